// Round 1
// baseline (775.792 us; speedup 1.0000x reference)
//
#include <hip/hip_runtime.h>

// Problem constants
static constexpr int Bb = 8, Nn = 16384, Cc = 256, KO = 48, KK = 16;
#define EPSBN 1e-5f

typedef short bf16x8 __attribute__((ext_vector_type(8)));
typedef float f32x4 __attribute__((ext_vector_type(4)));
typedef unsigned short u16x4 __attribute__((ext_vector_type(4)));

__device__ __forceinline__ unsigned short f2bf(float f) {
  unsigned u = __builtin_bit_cast(unsigned, f);
  u += 0x7FFFu + ((u >> 16) & 1u);   // round-to-nearest-even
  return (unsigned short)(u >> 16);
}

// Blocked LDS layout for a 64-point x 256-channel bf16 tile:
// element (p, c) lives at ushort index (c/8)*512 + p*8 + (c%8).
// -> ds_read_b128 of 8 consecutive channels is contiguous; lanes 0..15
//    (different p) hit distinct banks (2-way max, free).
#define LADDR(p, c) ((((c) >> 3) << 9) + ((p) << 3) + ((c) & 7))

// ---------------------------------------------------------------------------
// prep: weights fp32 -> bf16, BN scale/shift
// ---------------------------------------------------------------------------
__global__ void prep_k(const float* __restrict__ W1, const float* __restrict__ W2,
                       const float* __restrict__ W3, const float* __restrict__ Wo,
                       const float* __restrict__ g1, const float* __restrict__ bb1,
                       const float* __restrict__ m1, const float* __restrict__ v1,
                       const float* __restrict__ g2, const float* __restrict__ bb2,
                       const float* __restrict__ m2, const float* __restrict__ v2,
                       const float* __restrict__ g3, const float* __restrict__ bb3,
                       const float* __restrict__ m3, const float* __restrict__ v3,
                       unsigned short* __restrict__ W1b, unsigned short* __restrict__ W2b,
                       unsigned short* __restrict__ W3b, unsigned short* __restrict__ Wob,
                       float* __restrict__ st1, float* __restrict__ st2,
                       float* __restrict__ st3) {
  int gid = blockIdx.x * 256 + threadIdx.x;
  if (gid < 65536) W1b[gid] = f2bf(W1[gid]);
  else if (gid < 131072) W2b[gid - 65536] = f2bf(W2[gid - 65536]);
  else if (gid < 262144) W3b[gid - 131072] = f2bf(W3[gid - 131072]);
  else if (gid < 286720) Wob[gid - 262144] = f2bf(Wo[gid - 262144]);
  if (gid < 256) {
    float s = g1[gid] * rsqrtf(v1[gid] + EPSBN);
    st1[2 * gid] = s; st1[2 * gid + 1] = bb1[gid] - m1[gid] * s;
  } else if (gid < 512) {
    int i = gid - 256;
    float s = g2[i] * rsqrtf(v2[i] + EPSBN);
    st2[2 * i] = s; st2[2 * i + 1] = bb2[i] - m2[i] * s;
  } else if (gid < 1024) {
    int i = gid - 512;
    float s = g3[i] * rsqrtf(v3[i] + EPSBN);
    st3[2 * i] = s; st3[2 * i + 1] = bb3[i] - m3[i] * s;
  }
}

// ---------------------------------------------------------------------------
// fused backbone: 64 points/block, 4 waves.
// D[out_ch][point]: A-frag = W rows (contiguous), B-frag = x rows (contiguous).
// mfma_f32_16x16x32_bf16 C/D layout: col(=point)=lane&15, row(=ch)=(lane>>4)*4+reg.
// ---------------------------------------------------------------------------
__device__ __forceinline__ void gemm_layer(const unsigned short* __restrict__ src,
                                           unsigned short* __restrict__ dst,
                                           const unsigned short* __restrict__ Wg,
                                           const float* __restrict__ st, int tid) {
  const int lane = tid & 63;
  const int wave = tid >> 6;
  const int ln15 = lane & 15;
  const int q = lane >> 4;
  const f32x4 zero = {0.f, 0.f, 0.f, 0.f};
  f32x4 acc[4][4];
#pragma unroll
  for (int i = 0; i < 4; ++i)
#pragma unroll
    for (int j = 0; j < 4; ++j) acc[i][j] = zero;
  const int ch0 = wave * 64;
#pragma unroll
  for (int k0 = 0; k0 < 256; k0 += 32) {
    const int koff = k0 + q * 8;
    bf16x8 bfr[4], afr[4];
#pragma unroll
    for (int pt = 0; pt < 4; ++pt)
      bfr[pt] = *reinterpret_cast<const bf16x8*>(&src[((koff >> 3) << 9) + ((pt * 16 + ln15) << 3)]);
#pragma unroll
    for (int ct = 0; ct < 4; ++ct)
      afr[ct] = *reinterpret_cast<const bf16x8*>(&Wg[(ch0 + ct * 16 + ln15) * 256 + koff]);
#pragma unroll
    for (int ct = 0; ct < 4; ++ct)
#pragma unroll
      for (int pt = 0; pt < 4; ++pt)
        acc[ct][pt] = __builtin_amdgcn_mfma_f32_16x16x32_bf16(afr[ct], bfr[pt], acc[ct][pt], 0, 0, 0);
  }
  // epilogue: BN + ReLU, fp32 -> bf16, write blocked LDS
#pragma unroll
  for (int ct = 0; ct < 4; ++ct) {
    const int chl = ch0 + ct * 16 + q * 4;  // 4 consecutive output channels
    float s0[4], t0[4];
#pragma unroll
    for (int r = 0; r < 4; ++r) {
      s0[r] = st[2 * (chl + r)];
      t0[r] = st[2 * (chl + r) + 1];
    }
#pragma unroll
    for (int pt = 0; pt < 4; ++pt) {
      const int p = pt * 16 + ln15;
      u16x4 hv;
#pragma unroll
      for (int r = 0; r < 4; ++r) {
        float v = fmaxf(acc[ct][pt][r] * s0[r] + t0[r], 0.f);
        hv[r] = f2bf(v);
      }
      *reinterpret_cast<u16x4*>(&dst[LADDR(p, chl)]) = hv;
    }
  }
}

__device__ __forceinline__ void wo_partial(const unsigned short* __restrict__ src,
                                           const unsigned short* __restrict__ WoB,
                                           f32x4* accO, int tid) {
  const int lane = tid & 63;
  const int wave = tid >> 6;
  const int ln15 = lane & 15;
  const int q = lane >> 4;
#pragma unroll
  for (int k0 = 0; k0 < 256; k0 += 32) {
    const int koff = k0 + q * 8;
    bf16x8 bfr = *reinterpret_cast<const bf16x8*>(&src[((koff >> 3) << 9) + ((wave * 16 + ln15) << 3)]);
#pragma unroll
    for (int ot = 0; ot < 3; ++ot) {
      bf16x8 afr = *reinterpret_cast<const bf16x8*>(&WoB[(ot * 16 + ln15) * 512 + koff]);
      accO[ot] = __builtin_amdgcn_mfma_f32_16x16x32_bf16(afr, bfr, accO[ot], 0, 0, 0);
    }
  }
}

__global__ __launch_bounds__(256, 2) void backbone_k(
    const float* __restrict__ ff, const float* __restrict__ xyz,
    const unsigned short* __restrict__ W1b, const unsigned short* __restrict__ W2b,
    const unsigned short* __restrict__ W3b, const unsigned short* __restrict__ Wob,
    const float* __restrict__ st1, const float* __restrict__ st2,
    const float* __restrict__ st3, const float* __restrict__ bo,
    float* __restrict__ voted, float* __restrict__ kp_sum) {
  __shared__ unsigned short bufA[64 * 256];
  __shared__ unsigned short bufB[64 * 256];
  const int tid = threadIdx.x;
  const int b = blockIdx.x >> 8;
  const int n0 = (blockIdx.x & 255) * 64;

  // stage ff tile -> bufA (bf16, blocked layout)
  {
    const float* src = ff + (b * Nn + n0) * Cc;
#pragma unroll
    for (int i = 0; i < 16; ++i) {
      int p = (tid & 15) + 16 * (i & 3);
      int c4 = (tid >> 4) + 16 * (i >> 2);
      const float4 v = *reinterpret_cast<const float4*>(src + p * Cc + c4 * 4);
      u16x4 h;
      h.x = f2bf(v.x); h.y = f2bf(v.y); h.z = f2bf(v.z); h.w = f2bf(v.w);
      *reinterpret_cast<u16x4*>(&bufA[LADDR(p, c4 * 4)]) = h;
    }
  }
  __syncthreads();
  gemm_layer(bufA, bufB, W1b, st1, tid);
  __syncthreads();
  gemm_layer(bufB, bufA, W2b, st2, tid);
  __syncthreads();

  const f32x4 zero = {0.f, 0.f, 0.f, 0.f};
  f32x4 accO[3] = {zero, zero, zero};
#pragma unroll
  for (int h = 0; h < 2; ++h) {
    gemm_layer(bufA, bufB, W3b + h * 256 * 256, st3 + 512 * h, tid);
    __syncthreads();
    wo_partial(bufB, Wob + 256 * h, accO, tid);
    __syncthreads();
  }

  // epilogue: offsets + bo + xyz -> voted; block-partial sums -> kp_sum atomics
  const int lane = tid & 63;
  const int wave = tid >> 6;
  const int ln15 = lane & 15;
  const int q = lane >> 4;
  const int p = wave * 16 + ln15;
  const int n = n0 + p;
  const float* xp = xyz + (b * Nn + n) * 3;
  float xv[3] = {xp[0], xp[1], xp[2]};
  float* vrow = voted + (b * Nn + n) * KO;
#pragma unroll
  for (int ot = 0; ot < 3; ++ot) {
#pragma unroll
    for (int r = 0; r < 4; ++r) {
      int o = ot * 16 + q * 4 + r;  // o = k*3 + d
      float v = accO[ot][r] + bo[o] + xv[o % 3];
      vrow[o] = v;
      float s = v;
      s += __shfl_xor(s, 1, 64);
      s += __shfl_xor(s, 2, 64);
      s += __shfl_xor(s, 4, 64);
      s += __shfl_xor(s, 8, 64);
      if (ln15 == 0) atomicAdd(&kp_sum[b * KO + o], s);
    }
  }
}

// ---------------------------------------------------------------------------
// kp_pos finalize
// ---------------------------------------------------------------------------
__global__ void kpfinal_k(const float* __restrict__ kp_sum, float* __restrict__ out,
                          float* __restrict__ kp_ws) {
  int i = blockIdx.x * 256 + threadIdx.x;
  if (i < Bb * KO) {
    float v = kp_sum[i] * (1.0f / (float)Nn);
    out[i] = v;
    kp_ws[i] = v;
  }
}

// ---------------------------------------------------------------------------
// dist: per point, 16 distances -> dist[b][k][n] (coalesced in n)
// ---------------------------------------------------------------------------
__global__ void dist_k(const float* __restrict__ voted, const float* __restrict__ kp_ws,
                       float* __restrict__ dist) {
  __shared__ float kp[KO];
  const int b = blockIdx.x >> 6;
  const int n0 = (blockIdx.x & 63) * 256;
  if (threadIdx.x < KO) kp[threadIdx.x] = kp_ws[b * KO + threadIdx.x];
  __syncthreads();
  const int n = n0 + threadIdx.x;
  const float* vr = voted + (b * Nn + n) * KO;
  float v[KO];
#pragma unroll
  for (int j = 0; j < 12; ++j) {
    float4 t = *reinterpret_cast<const float4*>(vr + 4 * j);
    v[4 * j] = t.x; v[4 * j + 1] = t.y; v[4 * j + 2] = t.z; v[4 * j + 3] = t.w;
  }
#pragma unroll
  for (int k = 0; k < KK; ++k) {
    float dx = v[3 * k] - kp[3 * k];
    float dy = v[3 * k + 1] - kp[3 * k + 1];
    float dz = v[3 * k + 2] - kp[3 * k + 2];
    dist[((b * KK + k) << 14) + n] = sqrtf(dx * dx + dy * dy + dz * dz);
  }
}

// ---------------------------------------------------------------------------
// softmax stats: per (b,k): m = min dist, inv_s = 1/sum exp(m - d)
// ---------------------------------------------------------------------------
__global__ void softstat_k(const float* __restrict__ dist, float* __restrict__ ms) {
  __shared__ float red[4];
  const int bk = blockIdx.x;
  const int tid = threadIdx.x;
  const float4* dp4 = reinterpret_cast<const float4*>(dist + ((long)bk << 14));
  float mn = 1e30f;
  for (int i = tid; i < 4096; i += 256) {
    float4 t = dp4[i];
    mn = fminf(mn, fminf(fminf(t.x, t.y), fminf(t.z, t.w)));
  }
#pragma unroll
  for (int m = 1; m < 64; m <<= 1) mn = fminf(mn, __shfl_xor(mn, m, 64));
  if ((tid & 63) == 0) red[tid >> 6] = mn;
  __syncthreads();
  mn = fminf(fminf(red[0], red[1]), fminf(red[2], red[3]));
  __syncthreads();
  float sum = 0.f;
  for (int i = tid; i < 4096; i += 256) {
    float4 t = dp4[i];
    sum += __expf(mn - t.x) + __expf(mn - t.y) + __expf(mn - t.z) + __expf(mn - t.w);
  }
#pragma unroll
  for (int m = 1; m < 64; m <<= 1) sum += __shfl_xor(sum, m, 64);
  if ((tid & 63) == 0) red[tid >> 6] = sum;
  __syncthreads();
  if (tid == 0) {
    sum = red[0] + red[1] + red[2] + red[3];
    ms[bk] = mn;
    ms[128 + bk] = 1.0f / sum;
  }
}

// ---------------------------------------------------------------------------
// pooling: kp_feat[b][k][c] = sum_n ff[b][n][c] * w[b][n][k]   (atomics over n-chunks)
// ---------------------------------------------------------------------------
__global__ __launch_bounds__(256) void pool_k(const float* __restrict__ ff,
                                              const float* __restrict__ dist,
                                              const float* __restrict__ ms,
                                              float* __restrict__ kp_feat) {
  __shared__ float wt[512 * KK];
  const int b = blockIdx.x >> 5;
  const int n0 = (blockIdx.x & 31) * 512;
  const int tid = threadIdx.x;
#pragma unroll
  for (int i = 0; i < 32; ++i) {
    int idx = i * 256 + tid;
    int k = idx >> 9;
    int p = idx & 511;
    float m = ms[b * KK + k];
    float is = ms[128 + b * KK + k];
    float d = dist[((b * KK + k) << 14) + n0 + p];
    wt[p * KK + k] = __expf(m - d) * is;
  }
  __syncthreads();
  float acc[KK];
#pragma unroll
  for (int k = 0; k < KK; ++k) acc[k] = 0.f;
  const float* fp = ff + (b * Nn + n0) * Cc + tid;
  for (int p = 0; p < 512; ++p) {
    float f = fp[p * Cc];
    const float4* w4 = reinterpret_cast<const float4*>(&wt[p * KK]);
#pragma unroll
    for (int j = 0; j < 4; ++j) {
      float4 w = w4[j];
      acc[4 * j] += f * w.x;
      acc[4 * j + 1] += f * w.y;
      acc[4 * j + 2] += f * w.z;
      acc[4 * j + 3] += f * w.w;
    }
  }
#pragma unroll
  for (int k = 0; k < KK; ++k)
    atomicAdd(&kp_feat[(b * KK + k) * Cc + tid], acc[k]);
}

// ---------------------------------------------------------------------------
// keypoint MLP: one block per (b,k) point, fp32
// ---------------------------------------------------------------------------
__global__ __launch_bounds__(256) void mlp_k(
    const float* __restrict__ kp_feat,
    const float* __restrict__ Wm1, const float* __restrict__ gm1,
    const float* __restrict__ bm1, const float* __restrict__ mm1,
    const float* __restrict__ vm1,
    const float* __restrict__ Wm2, const float* __restrict__ gm2,
    const float* __restrict__ bm2, const float* __restrict__ mm2,
    const float* __restrict__ vm2,
    const float* __restrict__ Wm3, float* __restrict__ out) {
  __shared__ float xa[256];
  __shared__ float xb[256];
  const int bk = blockIdx.x;
  const int d = threadIdx.x;
  xa[d] = kp_feat[bk * 256 + d];
  __syncthreads();
  // layer 1
  float acc = 0.f;
  {
    const float4* w4 = reinterpret_cast<const float4*>(Wm1 + d * 256);
    const float4* x4 = reinterpret_cast<const float4*>(xa);
    for (int c = 0; c < 64; ++c) {
      float4 w = w4[c], x = x4[c];
      acc += w.x * x.x + w.y * x.y + w.z * x.z + w.w * x.w;
    }
  }
  {
    float s = gm1[d] * rsqrtf(vm1[d] + EPSBN);
    xb[d] = fmaxf(acc * s + (bm1[d] - mm1[d] * s), 0.f);
  }
  __syncthreads();
  // layer 2
  acc = 0.f;
  {
    const float4* w4 = reinterpret_cast<const float4*>(Wm2 + d * 256);
    const float4* x4 = reinterpret_cast<const float4*>(xb);
    for (int c = 0; c < 64; ++c) {
      float4 w = w4[c], x = x4[c];
      acc += w.x * x.x + w.y * x.y + w.z * x.z + w.w * x.w;
    }
  }
  {
    float s = gm2[d] * rsqrtf(vm2[d] + EPSBN);
    xa[d] = fmaxf(acc * s + (bm2[d] - mm2[d] * s), 0.f);
  }
  __syncthreads();
  // layer 3 (no BN/ReLU)
  acc = 0.f;
  {
    const float4* w4 = reinterpret_cast<const float4*>(Wm3 + d * 256);
    const float4* x4 = reinterpret_cast<const float4*>(xa);
    for (int c = 0; c < 64; ++c) {
      float4 w = w4[c], x = x4[c];
      acc += w.x * x.x + w.y * x.y + w.z * x.z + w.w * x.w;
    }
  }
  out[384 + bk * 256 + d] = acc;
}

// ---------------------------------------------------------------------------
// launch
// ---------------------------------------------------------------------------
extern "C" void kernel_launch(void* const* d_in, const int* in_sizes, int n_in,
                              void* d_out, int out_size, void* d_ws, size_t ws_size,
                              hipStream_t stream) {
  const float* ff  = (const float*)d_in[0];
  const float* xyz = (const float*)d_in[1];
  const float* W1 = (const float*)d_in[2];
  const float* g1 = (const float*)d_in[3];
  const float* b1 = (const float*)d_in[4];
  const float* m1 = (const float*)d_in[5];
  const float* v1 = (const float*)d_in[6];
  const float* W2 = (const float*)d_in[7];
  const float* g2 = (const float*)d_in[8];
  const float* b2 = (const float*)d_in[9];
  const float* m2 = (const float*)d_in[10];
  const float* v2 = (const float*)d_in[11];
  const float* W3 = (const float*)d_in[12];
  const float* g3 = (const float*)d_in[13];
  const float* b3 = (const float*)d_in[14];
  const float* m3 = (const float*)d_in[15];
  const float* v3 = (const float*)d_in[16];
  const float* Wo = (const float*)d_in[17];
  const float* bo = (const float*)d_in[18];
  const float* Wm1 = (const float*)d_in[19];
  const float* gm1 = (const float*)d_in[20];
  const float* bm1 = (const float*)d_in[21];
  const float* mm1 = (const float*)d_in[22];
  const float* vm1 = (const float*)d_in[23];
  const float* Wm2 = (const float*)d_in[24];
  const float* gm2 = (const float*)d_in[25];
  const float* bm2 = (const float*)d_in[26];
  const float* mm2 = (const float*)d_in[27];
  const float* vm2 = (const float*)d_in[28];
  const float* Wm3 = (const float*)d_in[29];
  float* out = (float*)d_out;

  // workspace carve-up (512B aligned)
  char* base = (char*)d_ws;
  size_t off = 0;
  auto carve = [&](size_t bytes) {
    char* p = base + off;
    off = (off + bytes + 511) & ~(size_t)511;
    return p;
  };
  unsigned short* W1b = (unsigned short*)carve(65536 * 2);
  unsigned short* W2b = (unsigned short*)carve(65536 * 2);
  unsigned short* W3b = (unsigned short*)carve(131072 * 2);
  unsigned short* Wob = (unsigned short*)carve(24576 * 2);
  float* st1 = (float*)carve(512 * 4);
  float* st2 = (float*)carve(512 * 4);
  float* st3 = (float*)carve(1024 * 4);
  float* voted = (float*)carve((size_t)Bb * Nn * KO * 4);      // 25.2 MB
  float* kp_sum = (float*)carve(Bb * KO * 4);
  float* kp_ws = (float*)carve(Bb * KO * 4);
  float* dist = (float*)carve((size_t)Bb * KK * Nn * 4);       // 8.4 MB
  float* ms = (float*)carve(256 * 4);
  float* kp_feat = (float*)carve(Bb * KK * Cc * 4);
  (void)ws_size; (void)n_in; (void)in_sizes; (void)out_size;

  hipMemsetAsync(kp_sum, 0, Bb * KO * 4, stream);
  hipMemsetAsync(kp_feat, 0, Bb * KK * Cc * 4, stream);

  prep_k<<<1120, 256, 0, stream>>>(W1, W2, W3, Wo, g1, b1, m1, v1, g2, b2, m2, v2,
                                   g3, b3, m3, v3, W1b, W2b, W3b, Wob, st1, st2, st3);
  backbone_k<<<2048, 256, 0, stream>>>(ff, xyz, W1b, W2b, W3b, Wob, st1, st2, st3,
                                       bo, voted, kp_sum);
  kpfinal_k<<<2, 256, 0, stream>>>(kp_sum, out, kp_ws);
  dist_k<<<512, 256, 0, stream>>>(voted, kp_ws, dist);
  softstat_k<<<128, 256, 0, stream>>>(dist, ms);
  pool_k<<<256, 256, 0, stream>>>(ff, dist, ms, kp_feat);
  mlp_k<<<128, 256, 0, stream>>>(kp_feat, Wm1, gm1, bm1, mm1, vm1,
                                 Wm2, gm2, bm2, mm2, vm2, Wm3, out);
}

// Round 2
// 445.992 us; speedup vs baseline: 1.7395x; 1.7395x over previous
//
#include <hip/hip_runtime.h>

// Problem constants
static constexpr int Bb = 8, Nn = 16384, Cc = 256, KO = 48, KK = 16;
#define EPSBN 1e-5f

typedef short bf16x8 __attribute__((ext_vector_type(8)));
typedef float f32x4 __attribute__((ext_vector_type(4)));
typedef unsigned short u16x4 __attribute__((ext_vector_type(4)));

__device__ __forceinline__ unsigned short f2bf(float f) {
  unsigned u = __builtin_bit_cast(unsigned, f);
  u += 0x7FFFu + ((u >> 16) & 1u);   // round-to-nearest-even
  return (unsigned short)(u >> 16);
}

// Blocked LDS layout for a 64-point x 256-channel bf16 tile:
// element (p, c) lives at ushort index (c/8)*512 + p*8 + (c%8).
#define LADDR(p, c) ((((c) >> 3) << 9) + ((p) << 3) + ((c) & 7))

// ---------------------------------------------------------------------------
// prep: weights fp32 -> bf16 in MFMA-fragment-major (swizzled) order.
// A-frag tile (16 out-ch x 32 k): lane = (r%16) | ((k%32)/8)<<4, j = k%8.
// Tile stored as 64 lanes x 8 ushorts contiguous (1KB). Wave load = lane*16B.
// ---------------------------------------------------------------------------
__global__ void prep_k(const float* __restrict__ W1, const float* __restrict__ W2,
                       const float* __restrict__ W3, const float* __restrict__ Wo,
                       const float* __restrict__ g1, const float* __restrict__ bb1,
                       const float* __restrict__ m1, const float* __restrict__ v1,
                       const float* __restrict__ g2, const float* __restrict__ bb2,
                       const float* __restrict__ m2, const float* __restrict__ v2,
                       const float* __restrict__ g3, const float* __restrict__ bb3,
                       const float* __restrict__ m3, const float* __restrict__ v3,
                       unsigned short* __restrict__ W1b, unsigned short* __restrict__ W2b,
                       unsigned short* __restrict__ W3b, unsigned short* __restrict__ Wob,
                       float* __restrict__ st1, float* __restrict__ st2,
                       float* __restrict__ st3) {
  int gid = blockIdx.x * 256 + threadIdx.x;
  if (gid < 65536) {
    int r = gid >> 8, k = gid & 255;
    int dst = (((r >> 4) * 8 + (k >> 5)) << 9) + (((r & 15) | (((k >> 3) & 3) << 4)) << 3) + (k & 7);
    W1b[dst] = f2bf(W1[gid]);
  } else if (gid < 131072) {
    int g = gid - 65536;
    int r = g >> 8, k = g & 255;
    int dst = (((r >> 4) * 8 + (k >> 5)) << 9) + (((r & 15) | (((k >> 3) & 3) << 4)) << 3) + (k & 7);
    W2b[dst] = f2bf(W2[g]);
  } else if (gid < 262144) {
    int g = gid - 131072;
    int r = g >> 8, k = g & 255;           // r in [0,512)
    int h = r >> 8, rr = r & 255;
    int dst = h * 65536 + ((((rr >> 4) * 8 + (k >> 5))) << 9) +
              (((rr & 15) | (((k >> 3) & 3) << 4)) << 3) + (k & 7);
    W3b[dst] = f2bf(W3[g]);
  } else if (gid < 286720) {
    int g = gid - 262144;
    int r = g >> 9, k = g & 511;           // Wo is 48 x 512
    int dst = (((r >> 4) * 16 + (k >> 5)) << 9) + (((r & 15) | (((k >> 3) & 3) << 4)) << 3) + (k & 7);
    Wob[dst] = f2bf(Wo[g]);
  }
  if (gid < 256) {
    float s = g1[gid] * rsqrtf(v1[gid] + EPSBN);
    st1[2 * gid] = s; st1[2 * gid + 1] = bb1[gid] - m1[gid] * s;
  } else if (gid < 512) {
    int i = gid - 256;
    float s = g2[i] * rsqrtf(v2[i] + EPSBN);
    st2[2 * i] = s; st2[2 * i + 1] = bb2[i] - m2[i] * s;
  } else if (gid < 1024) {
    int i = gid - 512;
    float s = g3[i] * rsqrtf(v3[i] + EPSBN);
    st3[2 * i] = s; st3[2 * i + 1] = bb3[i] - m3[i] * s;
  }
}

// ---------------------------------------------------------------------------
// fused backbone layer: 64 points/block, 4 waves; wave owns 64 out-channels.
// W is fragment-major: tile (ctg, kb) at ushort offset (ctg*8+kb)*512 + lane*8.
// Explicit cur/nxt register double-buffer on the k-loop.
// ---------------------------------------------------------------------------
__device__ __forceinline__ void gemm_layer(const unsigned short* __restrict__ src,
                                           unsigned short* __restrict__ dst,
                                           const unsigned short* __restrict__ Wsw,
                                           const float* __restrict__ st, int tid) {
  const int lane = tid & 63;
  const int wave = tid >> 6;
  const int ln15 = lane & 15;
  const int q = lane >> 4;
  f32x4 acc[4][4] = {};
  const unsigned short* wb = Wsw + ((wave * 32) << 9) + lane * 8;
  bf16x8 a_cur[4], b_cur[4], a_nxt[4], b_nxt[4];
#pragma unroll
  for (int ct = 0; ct < 4; ++ct)
    a_cur[ct] = *reinterpret_cast<const bf16x8*>(wb + ((ct * 8) << 9));
#pragma unroll
  for (int pt = 0; pt < 4; ++pt)
    b_cur[pt] = *reinterpret_cast<const bf16x8*>(&src[(q << 9) + ((pt * 16 + ln15) << 3)]);
#pragma unroll
  for (int kb = 0; kb < 8; ++kb) {
    if (kb < 7) {
#pragma unroll
      for (int ct = 0; ct < 4; ++ct)
        a_nxt[ct] = *reinterpret_cast<const bf16x8*>(wb + ((ct * 8 + kb + 1) << 9));
#pragma unroll
      for (int pt = 0; pt < 4; ++pt)
        b_nxt[pt] = *reinterpret_cast<const bf16x8*>(&src[(((kb + 1) * 4 + q) << 9) + ((pt * 16 + ln15) << 3)]);
    }
#pragma unroll
    for (int ct = 0; ct < 4; ++ct)
#pragma unroll
      for (int pt = 0; pt < 4; ++pt)
        acc[ct][pt] = __builtin_amdgcn_mfma_f32_16x16x32_bf16(a_cur[ct], b_cur[pt], acc[ct][pt], 0, 0, 0);
    if (kb < 7) {
#pragma unroll
      for (int ct = 0; ct < 4; ++ct) a_cur[ct] = a_nxt[ct];
#pragma unroll
      for (int pt = 0; pt < 4; ++pt) b_cur[pt] = b_nxt[pt];
    }
  }
  // epilogue: BN + ReLU, fp32 -> bf16, write blocked LDS
  const int ch0 = wave * 64;
#pragma unroll
  for (int ct = 0; ct < 4; ++ct) {
    const int chl = ch0 + ct * 16 + q * 4;
    float s0[4], t0[4];
#pragma unroll
    for (int r = 0; r < 4; ++r) {
      s0[r] = st[2 * (chl + r)];
      t0[r] = st[2 * (chl + r) + 1];
    }
#pragma unroll
    for (int pt = 0; pt < 4; ++pt) {
      const int p = pt * 16 + ln15;
      u16x4 hv;
#pragma unroll
      for (int r = 0; r < 4; ++r) {
        float v = fmaxf(acc[ct][pt][r] * s0[r] + t0[r], 0.f);
        hv[r] = f2bf(v);
      }
      *reinterpret_cast<u16x4*>(&dst[LADDR(p, chl)]) = hv;
    }
  }
}

// Wo partial: wave owns its 16 points across all 48 output rows.
// Wo fragment-major tile (ot, kbg) at (ot*16+kbg)*512 + lane*8, kbg = 8h+kb.
__device__ __forceinline__ void wo_partial(const unsigned short* __restrict__ src,
                                           const unsigned short* __restrict__ Wosw,
                                           int h, f32x4* accO, int tid) {
  const int lane = tid & 63;
  const int wave = tid >> 6;
  const int ln15 = lane & 15;
  const int q = lane >> 4;
#pragma unroll
  for (int kb = 0; kb < 8; ++kb) {
    bf16x8 bfr = *reinterpret_cast<const bf16x8*>(&src[((kb * 4 + q) << 9) + ((wave * 16 + ln15) << 3)]);
#pragma unroll
    for (int ot = 0; ot < 3; ++ot) {
      bf16x8 afr = *reinterpret_cast<const bf16x8*>(&Wosw[((ot * 16 + 8 * h + kb) << 9) + lane * 8]);
      accO[ot] = __builtin_amdgcn_mfma_f32_16x16x32_bf16(afr, bfr, accO[ot], 0, 0, 0);
    }
  }
}

__global__ __launch_bounds__(256, 2) void backbone_k(
    const float* __restrict__ ff, const float* __restrict__ xyz,
    const unsigned short* __restrict__ W1b, const unsigned short* __restrict__ W2b,
    const unsigned short* __restrict__ W3b, const unsigned short* __restrict__ Wob,
    const float* __restrict__ st1, const float* __restrict__ st2,
    const float* __restrict__ st3, const float* __restrict__ bo,
    float* __restrict__ voted, float* __restrict__ block_part) {
  __shared__ unsigned short bufA[64 * 256];
  __shared__ unsigned short bufB[64 * 256];
  __shared__ float sh_part[4][KO];
  const int tid = threadIdx.x;
  const int b = blockIdx.x >> 8;
  const int n0 = (blockIdx.x & 255) * 64;

  // stage ff tile -> bufA (bf16, blocked layout)
  {
    const float* src = ff + (b * Nn + n0) * Cc;
#pragma unroll
    for (int i = 0; i < 16; ++i) {
      int p = (tid & 15) + 16 * (i & 3);
      int c4 = (tid >> 4) + 16 * (i >> 2);
      const float4 v = *reinterpret_cast<const float4*>(src + p * Cc + c4 * 4);
      u16x4 h;
      h.x = f2bf(v.x); h.y = f2bf(v.y); h.z = f2bf(v.z); h.w = f2bf(v.w);
      *reinterpret_cast<u16x4*>(&bufA[LADDR(p, c4 * 4)]) = h;
    }
  }
  __syncthreads();
  gemm_layer(bufA, bufB, W1b, st1, tid);
  __syncthreads();
  gemm_layer(bufB, bufA, W2b, st2, tid);
  __syncthreads();

  f32x4 accO[3] = {};
#pragma unroll
  for (int h = 0; h < 2; ++h) {
    gemm_layer(bufA, bufB, W3b + h * 65536, st3 + 512 * h, tid);
    __syncthreads();
    wo_partial(bufB, Wob, h, accO, tid);
    __syncthreads();
  }

  // epilogue: offsets + bo + xyz -> voted; LDS-reduced block partials (no atomics)
  const int lane = tid & 63;
  const int wave = tid >> 6;
  const int ln15 = lane & 15;
  const int q = lane >> 4;
  const int p = wave * 16 + ln15;
  const int n = n0 + p;
  const float* xp = xyz + (b * Nn + n) * 3;
  float xv[3] = {xp[0], xp[1], xp[2]};
  float* vrow = voted + (b * Nn + n) * KO;
#pragma unroll
  for (int ot = 0; ot < 3; ++ot) {
#pragma unroll
    for (int r = 0; r < 4; ++r) {
      int o = ot * 16 + q * 4 + r;  // o = k*3 + d
      float v = accO[ot][r] + bo[o] + xv[o % 3];
      vrow[o] = v;
      float s = v;
      s += __shfl_xor(s, 1, 64);
      s += __shfl_xor(s, 2, 64);
      s += __shfl_xor(s, 4, 64);
      s += __shfl_xor(s, 8, 64);
      if (ln15 == 0) sh_part[wave][o] = s;
    }
  }
  __syncthreads();
  if (tid < KO) {
    float t = sh_part[0][tid] + sh_part[1][tid] + sh_part[2][tid] + sh_part[3][tid];
    block_part[blockIdx.x * KO + tid] = t;
  }
}

// ---------------------------------------------------------------------------
// kp_pos finalize: reduce 256 block partials per (b,o)
// ---------------------------------------------------------------------------
__global__ __launch_bounds__(256) void kpfinal_k(const float* __restrict__ block_part,
                                                 float* __restrict__ out,
                                                 float* __restrict__ kp_ws) {
  __shared__ float red[4];
  const int b = blockIdx.x / KO;
  const int o = blockIdx.x % KO;
  const int tid = threadIdx.x;
  float s = block_part[((b << 8) + tid) * KO + o];
#pragma unroll
  for (int m = 1; m < 64; m <<= 1) s += __shfl_xor(s, m, 64);
  if ((tid & 63) == 0) red[tid >> 6] = s;
  __syncthreads();
  if (tid == 0) {
    float v = (red[0] + red[1] + red[2] + red[3]) * (1.0f / (float)Nn);
    out[b * KO + o] = v;
    kp_ws[b * KO + o] = v;
  }
}

// ---------------------------------------------------------------------------
// dist: per point, 16 exp(-dist) -> wexp[b][k][n]; per-(b,k) sums via atomics
// (exp(-d) <= 1, no max-subtraction needed)
// ---------------------------------------------------------------------------
__global__ __launch_bounds__(256) void dist_k(const float* __restrict__ voted,
                                              const float* __restrict__ kp_ws,
                                              float* __restrict__ wexp,
                                              float* __restrict__ wsum) {
  __shared__ float kp[KO];
  __shared__ float red[64];
  const int b = blockIdx.x >> 6;
  const int n0 = (blockIdx.x & 63) * 256;
  const int tid = threadIdx.x;
  if (tid < KO) kp[tid] = kp_ws[b * KO + tid];
  __syncthreads();
  const int n = n0 + tid;
  const float* vr = voted + (b * Nn + n) * KO;
  float v[KO];
#pragma unroll
  for (int j = 0; j < 12; ++j) {
    float4 t = *reinterpret_cast<const float4*>(vr + 4 * j);
    v[4 * j] = t.x; v[4 * j + 1] = t.y; v[4 * j + 2] = t.z; v[4 * j + 3] = t.w;
  }
  float e[KK];
#pragma unroll
  for (int k = 0; k < KK; ++k) {
    float dx = v[3 * k] - kp[3 * k];
    float dy = v[3 * k + 1] - kp[3 * k + 1];
    float dz = v[3 * k + 2] - kp[3 * k + 2];
    e[k] = __expf(-sqrtf(dx * dx + dy * dy + dz * dz));
    wexp[((b * KK + k) << 14) + n] = e[k];
  }
  const int wave = tid >> 6;
  const int lane = tid & 63;
#pragma unroll
  for (int k = 0; k < KK; ++k) {
    float s = e[k];
#pragma unroll
    for (int m = 1; m < 64; m <<= 1) s += __shfl_xor(s, m, 64);
    if (lane == 0) red[wave * KK + k] = s;
  }
  __syncthreads();
  if (tid < KK) {
    float s = red[tid] + red[KK + tid] + red[2 * KK + tid] + red[3 * KK + tid];
    atomicAdd(&wsum[b * KK + tid], s);
  }
}

// ---------------------------------------------------------------------------
// pooling: kp_feat[b][k][c] = sum_n ff[b][n][c] * wexp[b][k][n] / wsum[b][k]
// ---------------------------------------------------------------------------
__global__ __launch_bounds__(256) void pool_k(const float* __restrict__ ff,
                                              const float* __restrict__ wexp,
                                              const float* __restrict__ wsum,
                                              float* __restrict__ kp_feat) {
  __shared__ float wt[256 * KK];   // 16 KB
  const int b = blockIdx.x >> 6;
  const int n0 = (blockIdx.x & 63) * 256;
  const int tid = threadIdx.x;
#pragma unroll
  for (int i = 0; i < KK; ++i) {
    float inv = 1.0f / wsum[b * KK + i];
    wt[tid * KK + i] = wexp[((b * KK + i) << 14) + n0 + tid] * inv;
  }
  __syncthreads();
  float acc[KK];
#pragma unroll
  for (int k = 0; k < KK; ++k) acc[k] = 0.f;
  const float* fp = ff + (b * Nn + n0) * Cc + tid;
  for (int p = 0; p < 256; ++p) {
    float f = fp[p * Cc];
    const float4* w4 = reinterpret_cast<const float4*>(&wt[p * KK]);
#pragma unroll
    for (int j = 0; j < 4; ++j) {
      float4 w = w4[j];
      acc[4 * j] += f * w.x;
      acc[4 * j + 1] += f * w.y;
      acc[4 * j + 2] += f * w.z;
      acc[4 * j + 3] += f * w.w;
    }
  }
#pragma unroll
  for (int k = 0; k < KK; ++k)
    atomicAdd(&kp_feat[(b * KK + k) * Cc + tid], acc[k]);
}

// ---------------------------------------------------------------------------
// keypoint MLP: one block per (b,k) point, fp32
// ---------------------------------------------------------------------------
__global__ __launch_bounds__(256) void mlp_k(
    const float* __restrict__ kp_feat,
    const float* __restrict__ Wm1, const float* __restrict__ gm1,
    const float* __restrict__ bm1, const float* __restrict__ mm1,
    const float* __restrict__ vm1,
    const float* __restrict__ Wm2, const float* __restrict__ gm2,
    const float* __restrict__ bm2, const float* __restrict__ mm2,
    const float* __restrict__ vm2,
    const float* __restrict__ Wm3, float* __restrict__ out) {
  __shared__ float xa[256];
  __shared__ float xb[256];
  const int bk = blockIdx.x;
  const int d = threadIdx.x;
  xa[d] = kp_feat[bk * 256 + d];
  __syncthreads();
  float acc = 0.f;
  {
    const float4* w4 = reinterpret_cast<const float4*>(Wm1 + d * 256);
    const float4* x4 = reinterpret_cast<const float4*>(xa);
    for (int c = 0; c < 64; ++c) {
      float4 w = w4[c], x = x4[c];
      acc += w.x * x.x + w.y * x.y + w.z * x.z + w.w * x.w;
    }
  }
  {
    float s = gm1[d] * rsqrtf(vm1[d] + EPSBN);
    xb[d] = fmaxf(acc * s + (bm1[d] - mm1[d] * s), 0.f);
  }
  __syncthreads();
  acc = 0.f;
  {
    const float4* w4 = reinterpret_cast<const float4*>(Wm2 + d * 256);
    const float4* x4 = reinterpret_cast<const float4*>(xb);
    for (int c = 0; c < 64; ++c) {
      float4 w = w4[c], x = x4[c];
      acc += w.x * x.x + w.y * x.y + w.z * x.z + w.w * x.w;
    }
  }
  {
    float s = gm2[d] * rsqrtf(vm2[d] + EPSBN);
    xa[d] = fmaxf(acc * s + (bm2[d] - mm2[d] * s), 0.f);
  }
  __syncthreads();
  acc = 0.f;
  {
    const float4* w4 = reinterpret_cast<const float4*>(Wm3 + d * 256);
    const float4* x4 = reinterpret_cast<const float4*>(xa);
    for (int c = 0; c < 64; ++c) {
      float4 w = w4[c], x = x4[c];
      acc += w.x * x.x + w.y * x.y + w.z * x.z + w.w * x.w;
    }
  }
  out[384 + bk * 256 + d] = acc;
}

// ---------------------------------------------------------------------------
// launch
// ---------------------------------------------------------------------------
extern "C" void kernel_launch(void* const* d_in, const int* in_sizes, int n_in,
                              void* d_out, int out_size, void* d_ws, size_t ws_size,
                              hipStream_t stream) {
  const float* ff  = (const float*)d_in[0];
  const float* xyz = (const float*)d_in[1];
  const float* W1 = (const float*)d_in[2];
  const float* g1 = (const float*)d_in[3];
  const float* b1 = (const float*)d_in[4];
  const float* m1 = (const float*)d_in[5];
  const float* v1 = (const float*)d_in[6];
  const float* W2 = (const float*)d_in[7];
  const float* g2 = (const float*)d_in[8];
  const float* b2 = (const float*)d_in[9];
  const float* m2 = (const float*)d_in[10];
  const float* v2 = (const float*)d_in[11];
  const float* W3 = (const float*)d_in[12];
  const float* g3 = (const float*)d_in[13];
  const float* b3 = (const float*)d_in[14];
  const float* m3 = (const float*)d_in[15];
  const float* v3 = (const float*)d_in[16];
  const float* Wo = (const float*)d_in[17];
  const float* bo = (const float*)d_in[18];
  const float* Wm1 = (const float*)d_in[19];
  const float* gm1 = (const float*)d_in[20];
  const float* bm1 = (const float*)d_in[21];
  const float* mm1 = (const float*)d_in[22];
  const float* vm1 = (const float*)d_in[23];
  const float* Wm2 = (const float*)d_in[24];
  const float* gm2 = (const float*)d_in[25];
  const float* bm2 = (const float*)d_in[26];
  const float* mm2 = (const float*)d_in[27];
  const float* vm2 = (const float*)d_in[28];
  const float* Wm3 = (const float*)d_in[29];
  float* out = (float*)d_out;

  char* base = (char*)d_ws;
  size_t off = 0;
  auto carve = [&](size_t bytes) {
    char* p = base + off;
    off = (off + bytes + 511) & ~(size_t)511;
    return p;
  };
  unsigned short* W1b = (unsigned short*)carve(65536 * 2);
  unsigned short* W2b = (unsigned short*)carve(65536 * 2);
  unsigned short* W3b = (unsigned short*)carve(131072 * 2);
  unsigned short* Wob = (unsigned short*)carve(24576 * 2);
  float* st1 = (float*)carve(512 * 4);
  float* st2 = (float*)carve(512 * 4);
  float* st3 = (float*)carve(1024 * 4);
  float* voted = (float*)carve((size_t)Bb * Nn * KO * 4);      // 25.2 MB
  float* block_part = (float*)carve((size_t)2048 * KO * 4);    // 393 KB
  float* kp_ws = (float*)carve(Bb * KO * 4);
  float* wexp = (float*)carve((size_t)Bb * KK * Nn * 4);       // 8.4 MB
  float* wsum = (float*)carve(Bb * KK * 4);
  float* kp_feat = (float*)carve(Bb * KK * Cc * 4);
  (void)ws_size; (void)n_in; (void)in_sizes; (void)out_size;

  hipMemsetAsync(wsum, 0, Bb * KK * 4, stream);
  hipMemsetAsync(kp_feat, 0, Bb * KK * Cc * 4, stream);

  prep_k<<<1120, 256, 0, stream>>>(W1, W2, W3, Wo, g1, b1, m1, v1, g2, b2, m2, v2,
                                   g3, b3, m3, v3, W1b, W2b, W3b, Wob, st1, st2, st3);
  backbone_k<<<2048, 256, 0, stream>>>(ff, xyz, W1b, W2b, W3b, Wob, st1, st2, st3,
                                       bo, voted, block_part);
  kpfinal_k<<<Bb * KO, 256, 0, stream>>>(block_part, out, kp_ws);
  dist_k<<<512, 256, 0, stream>>>(voted, kp_ws, wexp, wsum);
  pool_k<<<512, 256, 0, stream>>>(ff, wexp, wsum, kp_feat);
  mlp_k<<<128, 256, 0, stream>>>(kp_feat, Wm1, gm1, bm1, mm1, vm1,
                                 Wm2, gm2, bm2, mm2, vm2, Wm3, out);
}